// Round 14
// baseline (164.443 us; speedup 1.0000x reference)
//
#include <hip/hip_runtime.h>

namespace {

constexpr int B_ = 128;
constexpr int T_ = 4096;
constexpr int BT = B_ * T_;
constexpr int CT = 64;  // conv t-tile (4-wave blocks, 7 blocks/CU)
constexpr unsigned NOINS = 0xFFFFFFFFu;  // "do not insert" sentinel (invalid/masked lane)

// workspace layout (float offsets)
constexpr size_t OFF_W1F = 0;                     // 8 frags * 64 * 8 f16
constexpr size_t OFF_W2F = 2048;                  // 40 frags * 64 * 8 f16
constexpr size_t OFF_F16 = 16384;                 // feats16: B*T*10 halfs = B*T*5 dwords
constexpr size_t OFF_MET = OFF_F16 + (size_t)BT * 5;   // met: float4 per (b,t)
constexpr size_t OFF_LP  = OFF_MET + (size_t)BT * 4;

typedef _Float16 half8 __attribute__((ext_vector_type(8)));
typedef _Float16 half4 __attribute__((ext_vector_type(4)));
typedef _Float16 half2_t __attribute__((ext_vector_type(2)));
typedef float f32x4 __attribute__((ext_vector_type(4)));

__device__ __forceinline__ float clip01(float x) { return fminf(fmaxf(x, 0.f), 1.f); }

// tanh-GELU as sigmoid: x*sigmoid(1.5957691*(x+0.044715x^3)), 7 VALU ops.
__device__ __forceinline__ float gelu_tanh(float x) {
  float x2 = x * x;
  float q = x * __builtin_fmaf(-0.10294444f, x2, -2.3022077f);
  float e = __builtin_amdgcn_exp2f(q);
  return x * __builtin_amdgcn_rcpf(1.0f + e);
}

// rcp + one Newton step: <=1 ulp vs exact divide for normal inputs (dt >= 1e-3)
__device__ __forceinline__ float rcp_nr(float d) {
  float r = __builtin_amdgcn_rcpf(d);
  return r * __builtin_fmaf(-d, r, 2.0f);
}

// |atan2(y,x)| in [0,pi]; poly err <= ~1e-5 rad; exact corner semantics.
__device__ __forceinline__ float fabs_atan2_fast(float y, float x) {
  float ay = fabsf(y), ax = fabsf(x);
  float mn = fminf(ax, ay), mx = fmaxf(ax, ay);
  float rc = rcp_nr(mx);
  float r = (mx > 0.f) ? mn * rc : 0.f;
  float s = r * r;
  float p = __builtin_fmaf(s, -0.01172120f, 0.05265332f);
  p = __builtin_fmaf(s, p, -0.11643287f);
  p = __builtin_fmaf(s, p, 0.19354346f);
  p = __builtin_fmaf(s, p, -0.33262347f);
  p = __builtin_fmaf(s, p, 0.99997726f);
  float t = r * p;
  if (ay > ax) t = 1.5707963267948966f - t;
  if (x < 0.f) t = 3.141592653589793f - t;
  return t;
}

// feature math for (b,t) — same values as round-4 featurize_k
__device__ __forceinline__ void compute_feats(
    const float* __restrict__ tr, const float* __restrict__ iv,
    const float* __restrict__ mk, const float* __restrict__ om, int t,
    float* __restrict__ f /*10*/, float* anv_out, float* scv_out, float* otv_out) {
  float m  = mk[t];
  float m1 = (t >= 1) ? mk[t - 1] : 0.f;
  float m2 = (t >= 2) ? mk[t - 2] : 0.f;
  float pm01 = (m > 0.5f && m1 > 0.5f) ? 1.f : 0.f;
  float pm12 = (m1 > 0.5f && m2 > 0.5f) ? 1.f : 0.f;
  float x0x = tr[2 * t] * m, x0y = tr[2 * t + 1] * m;
  float x1x = 0.f, x1y = 0.f, x2x = 0.f, x2y = 0.f;
  if (t >= 1) { x1x = tr[2 * (t - 1)] * m1; x1y = tr[2 * (t - 1) + 1] * m1; }
  if (t >= 2) { x2x = tr[2 * (t - 2)] * m2; x2y = tr[2 * (t - 2) + 1] * m2; }
  float dt0 = fmaxf(iv[t], 1e-3f);
  float dt1 = (t >= 1) ? fmaxf(iv[t - 1], 1e-3f) : 1e-3f;
  float inv0 = rcp_nr(dt0);
  float inv1 = rcp_nr(dt1);
  float vx = 0.f, vy = 0.f, v1x = 0.f, v1y = 0.f;
  if (t >= 1) { vx = (x0x - x1x) * pm01 * inv0 * m; vy = (x0y - x1y) * pm01 * inv0 * m; }
  if (t >= 2) { v1x = (x1x - x2x) * pm12 * inv1 * m1; v1y = (x1y - x2y) * pm12 * inv1 * m1; }
  float ax = 0.f, ay = 0.f;
  if (t >= 1) { ax = (vx - v1x) * pm01 * inv0 * m; ay = (vy - v1y) * pm01 * inv0 * m; }
  float s2 = vx * vx + vy * vy;
  float speed = (s2 > 0.f ? sqrtf(s2) : 0.f) * m;
  float s21 = v1x * v1x + v1y * v1y;
  float speed1 = (s21 > 0.f ? sqrtf(s21) : 0.f) * m1;
  float scv = (t >= 1) ? fabsf((speed - speed1) * pm01) * m : 0.f;
  float a2 = ax * ax + ay * ay;
  float anv = (a2 > 0.f ? sqrtf(a2) : 0.f) * m;
  float hcv = 0.f;
  if (t >= 1) {
    bool z0 = (vx == 0.f && vy == 0.f);
    bool z1 = (v1x == 0.f && v1y == 0.f);
    float yy, xx;
    if (z1)      { yy = vy;  xx = vx; }
    else if (z0) { yy = v1y; xx = v1x; }
    else { yy = vy * v1x - vx * v1y; xx = vx * v1x + vy * v1y; }
    hcv = fabs_atan2_fast(yy, xx) * pm01 * m;
  }
  float obs = om[t] * m;
  float otv = (t >= 1) ? fminf(fabsf(om[t] - om[t - 1]) * pm01 * m, 1.f) : 0.f;
  float itf = iv[t] * m;
  f[0] = x0x; f[1] = x0y; f[2] = vx; f[3] = vy; f[4] = ax; f[5] = ay;
  f[6] = speed; f[7] = hcv; f[8] = itf; f[9] = obs;
  *anv_out = anv; *scv_out = scv; *otv_out = otv;
}

// ---------------- Kernel A: featurize -> f16 feats + packed float4 metrics + repack ----------------
__global__ __launch_bounds__(256)
void featurize_k(const float* __restrict__ traj, const float* __restrict__ intervals,
                 const float* __restrict__ amask, const float* __restrict__ omask,
                 const float* __restrict__ w1g, const float* __restrict__ w2g,
                 _Float16* __restrict__ feats16, float4* __restrict__ met,
                 half8* __restrict__ w1f, half8* __restrict__ w2f) {
  int idx = blockIdx.x * 256 + threadIdx.x;
  int b = idx >> 12;
  int t = idx & (T_ - 1);
  float f[10], anv, scv, otv;
  compute_feats(traj + (size_t)b * T_ * 2, intervals + (size_t)b * T_,
                amask + (size_t)b * T_, omask + (size_t)b * T_, t, f, &anv, &scv, &otv);
  half2_t* fd = reinterpret_cast<half2_t*>(feats16) + (size_t)idx * 5;
#pragma unroll
  for (int q = 0; q < 5; ++q) {
    half2_t pk;
    pk[0] = (_Float16)(f[2 * q] * 0.015625f);
    pk[1] = (_Float16)(f[2 * q + 1] * 0.015625f);
    fd[q] = pk;
  }
  met[idx] = make_float4(f[7], anv, scv, otv);

  if (blockIdx.x < 12) {
    int gid = blockIdx.x * 256 + threadIdx.x;
    if (gid < 48 * 64) {
      int fid = gid >> 6, lane = gid & 63;
      int qd = lane >> 4, ln = lane & 15;
      half8 v;
      if (fid < 8) {
        int m = fid >> 1, kk = fid & 1;
        int o = m * 16 + ln;
#pragma unroll
        for (int j = 0; j < 8; ++j) {
          int ck = kk * 32 + qd * 8 + j;
          float val = 0.f;
          if (ck < 50) { int k_ = ck / 10, c = ck - 10 * k_; val = w1g[o * 50 + c * 5 + k_]; }
          v[j] = (_Float16)val;
        }
        w1f[fid * 64 + lane] = v;
      } else {
        int f2 = fid - 8;
        int k = f2 >> 3, kk = (f2 >> 2) & 1, m = f2 & 3;
        int o = m * 16 + ln;
#pragma unroll
        for (int j = 0; j < 8; ++j) {
          int ic = kk * 32 + qd * 8 + j;
          v[j] = (_Float16)w2g[o * 320 + ic * 5 + k];
        }
        w2f[f2 * 64 + lane] = v;
      }
    }
  }
}

// ---------------- Kernel B: MFMA conv stack, CT=64; B-minimal phase-2 mapping ----------------
// Phase 2: wave = n-tile, computes ALL 64 output channels. B-fragment LDS loads
// drop 160 -> 40 per block (each loaded once); A comes from global (w2f 20 KB,
// L1-resident). conv3 reduces fully in-wave (sPart + final barrier deleted).
// Same MFMA sequence per accumulator -> bit-identical output.
__global__ __launch_bounds__(256, 7)
void conv_k(const _Float16* __restrict__ feats16, const half8* __restrict__ w1f,
            const float* __restrict__ b1g, const half8* __restrict__ w2f,
            const float* __restrict__ b2g, const float* __restrict__ w3g,
            const float* __restrict__ b3g, const float* __restrict__ amask,
            float* __restrict__ lp) {
  __shared__ _Float16 sIm[80 * 72];    // 11520 B
  __shared__ _Float16 sH1[68 * 72];    // 9792 B
  _Float16* sF16 = sH1;  // staging tile aliases sH1 until im2col barrier
  int tid = threadIdx.x;
  int lane = tid & 63, w = tid >> 6;
  int qd = lane >> 4, ln = lane & 15;
  int tile = blockIdx.x, b = blockIdx.y;
  int t0 = tile * CT;

  const unsigned* gfd = reinterpret_cast<const unsigned*>(feats16 + (size_t)b * T_ * 10);
  unsigned* sFd = reinterpret_cast<unsigned*>(sF16);
  int dbase = (t0 - 4) * 5;
  for (int s = tid; s < 360; s += 256) {
    int gi = dbase + s;
    sFd[s] = (gi >= 0 && gi < T_ * 5) ? gfd[gi] : 0u;
  }
  for (int s = tid; s < 560; s += 256) {
    int jt = s / 7, d = s - jt * 7;
    *reinterpret_cast<unsigned*>(&sIm[jt * 72 + 50 + 2 * d]) = 0u;
  }
  __syncthreads();
  unsigned* sId = reinterpret_cast<unsigned*>(sIm);
  for (int s = tid; s < 340; s += 256) {
    int jt = s / 5, k = s - jt * 5;
    const unsigned* src = sFd + (jt + k) * 5;
    unsigned* dst = sId + jt * 36 + k * 5;
#pragma unroll
    for (int q = 0; q < 5; ++q) dst[q] = src[q];
  }
  __syncthreads();  // sF16 dead; sH1 writes may begin

  // ---- phase 1: conv1; wave w owns output-channel group m = w ----
  {
    int m = w;
    half8 a1k0 = w1f[(m * 2 + 0) * 64 + lane];
    half8 a1k1 = w1f[(m * 2 + 1) * 64 + lane];
    f32x4 bv = *reinterpret_cast<const f32x4*>(&b1g[m * 16 + qd * 4]);
    f32x4 b1s;
#pragma unroll
    for (int r = 0; r < 4; ++r) b1s[r] = bv[r] * 0.015625f;
#pragma unroll
    for (int tl = 0; tl < 5; ++tl) {
      int jt = tl * 16 + ln;
      half8 bf0 = *reinterpret_cast<const half8*>(&sIm[jt * 72 + qd * 8]);
      half8 bf1 = *reinterpret_cast<const half8*>(&sIm[jt * 72 + 32 + qd * 8]);
      f32x4 acc = b1s;
      acc = __builtin_amdgcn_mfma_f32_16x16x32_f16(a1k0, bf0, acc, 0, 0, 0);
      acc = __builtin_amdgcn_mfma_f32_16x16x32_f16(a1k1, bf1, acc, 0, 0, 0);
      if (jt < 68) {
        int t = t0 - 2 + jt;
        bool inr = (t >= 0 && t < T_);
        half4 hv;
#pragma unroll
        for (int r = 0; r < 4; ++r) {
          float h = inr ? gelu_tanh(acc[r] * 64.f) * 0.0625f : 0.f;
          hv[r] = (_Float16)h;
        }
        *reinterpret_cast<half4*>(&sH1[jt * 72 + m * 16 + qd * 4]) = hv;
      }
    }
  }
  __syncthreads();

  // ---- phase 2: wave = n-tile (w), all 64 output channels; 1 B-load : 4 MFMA ----
  int ntile = w;
  f32x4 acc2[4];
#pragma unroll
  for (int m = 0; m < 4; ++m) {
    f32x4 bv = *reinterpret_cast<const f32x4*>(&b2g[m * 16 + qd * 4]);
#pragma unroll
    for (int r = 0; r < 4; ++r) acc2[m][r] = bv[r] * 0.0625f;
  }
#pragma unroll
  for (int k = 0; k < 5; ++k) {
#pragma unroll
    for (int kk = 0; kk < 2; ++kk) {
      half8 Bf = *reinterpret_cast<const half8*>(
          &sH1[(ntile * 16 + ln + k) * 72 + kk * 32 + qd * 8]);
      half8 A0 = w2f[((k * 2 + kk) * 4 + 0) * 64 + lane];
      half8 A1 = w2f[((k * 2 + kk) * 4 + 1) * 64 + lane];
      half8 A2 = w2f[((k * 2 + kk) * 4 + 2) * 64 + lane];
      half8 A3 = w2f[((k * 2 + kk) * 4 + 3) * 64 + lane];
      acc2[0] = __builtin_amdgcn_mfma_f32_16x16x32_f16(A0, Bf, acc2[0], 0, 0, 0);
      acc2[1] = __builtin_amdgcn_mfma_f32_16x16x32_f16(A1, Bf, acc2[1], 0, 0, 0);
      acc2[2] = __builtin_amdgcn_mfma_f32_16x16x32_f16(A2, Bf, acc2[2], 0, 0, 0);
      acc2[3] = __builtin_amdgcn_mfma_f32_16x16x32_f16(A3, Bf, acc2[3], 0, 0, 0);
    }
  }
  // ---- conv3 + sigmoid, fully in-wave ----
  float s = 0.f;
#pragma unroll
  for (int m = 0; m < 4; ++m) {
    f32x4 w3v = *reinterpret_cast<const f32x4*>(&w3g[m * 16 + qd * 4]);
#pragma unroll
    for (int r = 0; r < 4; ++r) s += w3v[r] * gelu_tanh(acc2[m][r] * 16.f);
  }
  s += __shfl_xor(s, 16);
  s += __shfl_xor(s, 32);
  if (lane < 16) {
    int t = t0 + ntile * 16 + lane;
    float m = amask[(size_t)b * T_ + t];
    float logit = s + b3g[0];
    float e = __builtin_amdgcn_exp2f(logit * -1.4426950408889634f);
    lp[(size_t)b * T_ + t] = m * __builtin_amdgcn_rcpf(1.f + e);
  }
}

// ---------------- low-barrier radix-select machinery ----------------
__device__ __forceinline__ void scan4096(unsigned (*hist)[4096], int j, int tid, int lane,
                                         int wv, unsigned (*sW)[16], uint4& v,
                                         unsigned& ps, unsigned& incl) {
  v = *reinterpret_cast<uint4*>(&hist[j][tid * 4]);
  uint4 zz = {0u, 0u, 0u, 0u};
  *reinterpret_cast<uint4*>(&hist[j][tid * 4]) = zz;
  ps = v.x + v.y + v.z + v.w;
  incl = ps;
#pragma unroll
  for (int off = 1; off < 64; off <<= 1) {
    unsigned tv = __shfl_up(incl, off, 64);
    if (lane >= off) incl += tv;
  }
  if (lane == 63) sW[j][wv] = incl;
}
__device__ __forceinline__ void resolve4096(const unsigned (*sW)[16], int j, int tid, int wv,
                                            uint4 v, unsigned ps, unsigned incl, unsigned k,
                                            unsigned* selb, unsigned* selk) {
  unsigned woff = 0;
  for (int i = 0; i < wv; ++i) woff += sW[j][i];
  incl += woff;
  unsigned excl = incl - ps;
  if (excl <= k && k < incl) {
    unsigned vv[4] = {v.x, v.y, v.z, v.w};
    unsigned run = excl;
    int c = 0;
#pragma unroll
    for (; c < 3; ++c) {
      if (run + vv[c] > k) break;
      run += vv[c];
    }
    *selb = (unsigned)(tid * 4 + c);
    *selk = k - run;
  }
}
__device__ __forceinline__ void scan256(unsigned (*hist)[4096], int j, int tid, int lane,
                                        int wv, unsigned (*sW)[16], unsigned& v,
                                        unsigned& incl) {
  v = (tid < 256) ? hist[j][tid] : 0u;
  if (tid < 256) hist[j][tid] = 0u;
  incl = v;
#pragma unroll
  for (int off = 1; off < 64; off <<= 1) {
    unsigned tv = __shfl_up(incl, off, 64);
    if (lane >= off) incl += tv;
  }
  if (lane == 63) sW[j][wv] = incl;
}
__device__ __forceinline__ void resolve256(const unsigned (*sW)[16], int j, int tid, int wv,
                                           unsigned v, unsigned incl, unsigned k,
                                           unsigned* selb) {
  unsigned woff = 0;
  for (int i = 0; i < wv; ++i) woff += sW[j][i];
  incl += woff;
  unsigned excl = incl - v;
  if (excl <= k && k < incl) *selb = (unsigned)tid;
}

// ---------------- Kernel C: selects + smooth + normalize + FINAL BLEND (per row) ----------------
__global__ __launch_bounds__(1024)
void ruleselect_k(const float4* __restrict__ met, const float* __restrict__ amask,
                  const float* __restrict__ lp, float* __restrict__ out) {
  __shared__ unsigned hist3[3][4096];
  __shared__ float vbuf[4096];
  __shared__ unsigned selB[2][4];
  __shared__ unsigned selK[2][4];
  __shared__ unsigned sW3[3][16];
  __shared__ float sM3[3][16];
  __shared__ int iCnt[16];
  int b = blockIdx.x, tid = threadIdx.x;
  int lane = tid & 63, wv = tid >> 6;
  const float* mk = amask + (size_t)b * T_;
  const float4* mrow = met + (size_t)b * T_;

  float mv0[4], mv1[4], mv2[4], otv[4], mreg[4];
  int cnt = 0;
#pragma unroll
  for (int r = 0; r < 4; ++r) {
    int t = tid + 1024 * r;
    float4 v = mrow[t];
    mv0[r] = v.x; mv1[r] = v.y; mv2[r] = v.z; otv[r] = v.w;
    mreg[r] = mk[t];
    cnt += (mreg[r] > 0.5f);
  }
#pragma unroll
  for (int off = 32; off; off >>= 1) cnt += __shfl_xor(cnt, off);
  if (lane == 0) iCnt[wv] = cnt;
  {
    unsigned* hflat = &hist3[0][0];
    for (int i = tid; i < 3 * 4096; i += 1024) hflat[i] = 0u;
  }
  unsigned u0[4], u1[4], u2[4];
  float mxa = 0.f, mxb = 0.f, mxc = 0.f;
#pragma unroll
  for (int r = 0; r < 4; ++r) {
    bool valid = mreg[r] > 0.5f;
    unsigned b0 = __float_as_uint(mv0[r]); if ((int)b0 < 0) b0 = 0u;
    unsigned b1 = __float_as_uint(mv1[r]); if ((int)b1 < 0) b1 = 0u;
    unsigned b2 = __float_as_uint(mv2[r]); if ((int)b2 < 0) b2 = 0u;
    u0[r] = valid ? b0 : NOINS;
    u1[r] = valid ? b1 : NOINS;
    u2[r] = valid ? b2 : NOINS;
    if (valid) {
      mxa = fmaxf(mxa, fabsf(mv0[r]));
      mxb = fmaxf(mxb, fabsf(mv1[r]));
      mxc = fmaxf(mxc, fabsf(mv2[r]));
    }
  }
#pragma unroll
  for (int off = 32; off; off >>= 1) {
    mxa = fmaxf(mxa, __shfl_xor(mxa, off));
    mxb = fmaxf(mxb, __shfl_xor(mxb, off));
    mxc = fmaxf(mxc, __shfl_xor(mxc, off));
  }
  if (lane == 0) { sM3[0][wv] = mxa; sM3[1][wv] = mxb; sM3[2][wv] = mxc; }
  __syncthreads();  // B1
  int n = 0;
#pragma unroll
  for (int i = 0; i < 16; ++i) n += iCnt[i];
  int cidx = (int)ceilf((float)n * 0.95f);
  if (cidx < 1) cidx = 1;
  unsigned kidx = (unsigned)(cidx - 1);
  if (kidx > (unsigned)(T_ - 1)) kidx = T_ - 1;
  float mx3a = sM3[0][0], mx3b = sM3[1][0], mx3c = sM3[2][0];
#pragma unroll
  for (int i = 1; i < 16; ++i) {
    mx3a = fmaxf(mx3a, sM3[0][i]);
    mx3b = fmaxf(mx3b, sM3[1][i]);
    mx3c = fmaxf(mx3c, sM3[2][i]);
  }

#pragma unroll
  for (int r = 0; r < 4; ++r) {
    if (u0[r] != NOINS) atomicAdd(&hist3[0][u0[r] >> 20], 1u);
    if (u1[r] != NOINS) atomicAdd(&hist3[1][u1[r] >> 20], 1u);
    if (u2[r] != NOINS) atomicAdd(&hist3[2][u2[r] >> 20], 1u);
  }
  __syncthreads();  // B2
  uint4 v40, v41, v42; unsigned ps0, ps1, ps2, in0, in1, in2;
  scan4096(hist3, 0, tid, lane, wv, sW3, v40, ps0, in0);
  scan4096(hist3, 1, tid, lane, wv, sW3, v41, ps1, in1);
  scan4096(hist3, 2, tid, lane, wv, sW3, v42, ps2, in2);
  __syncthreads();  // B3
  resolve4096(sW3, 0, tid, wv, v40, ps0, in0, kidx, &selB[1][0], &selK[1][0]);
  resolve4096(sW3, 1, tid, wv, v41, ps1, in1, kidx, &selB[1][1], &selK[1][1]);
  resolve4096(sW3, 2, tid, wv, v42, ps2, in2, kidx, &selB[1][2], &selK[1][2]);
  __syncthreads();  // B4
  unsigned p1_0 = selB[1][0], p1_1 = selB[1][1], p1_2 = selB[1][2];
  unsigned k2_0 = selK[1][0], k2_1 = selK[1][1], k2_2 = selK[1][2];
#pragma unroll
  for (int r = 0; r < 4; ++r) {
    if (u0[r] != NOINS && (u0[r] >> 20) == p1_0) atomicAdd(&hist3[0][(u0[r] >> 8) & 0xFFFu], 1u);
    if (u1[r] != NOINS && (u1[r] >> 20) == p1_1) atomicAdd(&hist3[1][(u1[r] >> 8) & 0xFFFu], 1u);
    if (u2[r] != NOINS && (u2[r] >> 20) == p1_2) atomicAdd(&hist3[2][(u2[r] >> 8) & 0xFFFu], 1u);
  }
  __syncthreads();  // B5
  scan4096(hist3, 0, tid, lane, wv, sW3, v40, ps0, in0);
  scan4096(hist3, 1, tid, lane, wv, sW3, v41, ps1, in1);
  scan4096(hist3, 2, tid, lane, wv, sW3, v42, ps2, in2);
  __syncthreads();  // B6
  resolve4096(sW3, 0, tid, wv, v40, ps0, in0, k2_0, &selB[0][0], &selK[0][0]);
  resolve4096(sW3, 1, tid, wv, v41, ps1, in1, k2_1, &selB[0][1], &selK[0][1]);
  resolve4096(sW3, 2, tid, wv, v42, ps2, in2, k2_2, &selB[0][2], &selK[0][2]);
  __syncthreads();  // B7
  unsigned p2_0 = selB[0][0], p2_1 = selB[0][1], p2_2 = selB[0][2];
  unsigned k3_0 = selK[0][0], k3_1 = selK[0][1], k3_2 = selK[0][2];
  unsigned pf0 = (p1_0 << 12) | p2_0, pf1 = (p1_1 << 12) | p2_1, pf2 = (p1_2 << 12) | p2_2;
#pragma unroll
  for (int r = 0; r < 4; ++r) {
    if (u0[r] != NOINS && (u0[r] >> 8) == pf0) atomicAdd(&hist3[0][u0[r] & 0xFFu], 1u);
    if (u1[r] != NOINS && (u1[r] >> 8) == pf1) atomicAdd(&hist3[1][u1[r] & 0xFFu], 1u);
    if (u2[r] != NOINS && (u2[r] >> 8) == pf2) atomicAdd(&hist3[2][u2[r] & 0xFFu], 1u);
  }
  __syncthreads();  // B8
  unsigned s80, s81, s82;
  scan256(hist3, 0, tid, lane, wv, sW3, s80, in0);
  scan256(hist3, 1, tid, lane, wv, sW3, s81, in1);
  scan256(hist3, 2, tid, lane, wv, sW3, s82, in2);
  __syncthreads();  // B9
  resolve256(sW3, 0, tid, wv, s80, in0, k3_0, &selB[1][0]);
  resolve256(sW3, 1, tid, wv, s81, in1, k3_1, &selB[1][1]);
  resolve256(sW3, 2, tid, wv, s82, in2, k3_2, &selB[1][2]);
  __syncthreads();  // B10
  float kth0 = fabsf(__uint_as_float((p1_0 << 20) | (p2_0 << 8) | selB[1][0]));
  float kth1 = fabsf(__uint_as_float((p1_1 << 20) | (p2_1 << 8) | selB[1][1]));
  float kth2 = fabsf(__uint_as_float((p1_2 << 20) | (p2_2 << 8) | selB[1][2]));
  float sc0 = fmaxf((kth0 < 1e-6f) ? mx3a : kth0, 1e-6f);
  float sc1 = fmaxf((kth1 < 1e-6f) ? mx3b : kth1, 1e-6f);
  float sc2 = fmaxf((kth2 < 1e-6f) ? mx3c : kth2, 1e-6f);

#pragma unroll
  for (int r = 0; r < 4; ++r) {
    int t = tid + 1024 * r;
    float v = 0.f;
    if (n > 0) {
      v = 0.35f * (mv0[r] / sc0) + 0.30f * (mv1[r] / sc1)
        + 0.25f * (mv2[r] / sc2) + 0.10f * otv[r];
    }
    vbuf[t] = v;
  }
  __syncthreads();  // B11
  float sm[4];
#pragma unroll
  for (int r = 0; r < 4; ++r) {
    int t = tid + 1024 * r;
    float s = 0.f;
#pragma unroll
    for (int d = -2; d <= 2; ++d) {
      int tt = t + d;
      if (tt >= 0 && tt < T_) s += vbuf[tt];
    }
    sm[r] = s * 0.2f * mreg[r];
  }
  // ---- 4th select (hist3[0], slot 3) ----
  unsigned uu[4];
  float mxs = 0.f;
#pragma unroll
  for (int r = 0; r < 4; ++r) {
    bool valid = mreg[r] > 0.5f;
    unsigned ub = __float_as_uint(sm[r]); if ((int)ub < 0) ub = 0u;
    uu[r] = valid ? ub : NOINS;
    if (valid) mxs = fmaxf(mxs, fabsf(sm[r]));
  }
#pragma unroll
  for (int off = 32; off; off >>= 1) mxs = fmaxf(mxs, __shfl_xor(mxs, off));
  if (lane == 0) sM3[0][wv] = mxs;
#pragma unroll
  for (int r = 0; r < 4; ++r)
    if (uu[r] != NOINS) atomicAdd(&hist3[0][uu[r] >> 20], 1u);
  __syncthreads();  // B12 — smooth reads of vbuf done; repurpose vbuf for lp
  const float* lprow = lp + (size_t)b * T_;
#pragma unroll
  for (int r = 0; r < 4; ++r) {
    int t = tid + 1024 * r;
    vbuf[t] = lprow[t];
  }
  float mx4 = sM3[0][0];
#pragma unroll
  for (int i = 1; i < 16; ++i) mx4 = fmaxf(mx4, sM3[0][i]);
  scan4096(hist3, 0, tid, lane, wv, sW3, v40, ps0, in0);
  __syncthreads();  // B13
  resolve4096(sW3, 0, tid, wv, v40, ps0, in0, kidx, &selB[1][3], &selK[1][3]);
  __syncthreads();  // B14
  unsigned q1 = selB[1][3], kq2 = selK[1][3];
#pragma unroll
  for (int r = 0; r < 4; ++r)
    if (uu[r] != NOINS && (uu[r] >> 20) == q1) atomicAdd(&hist3[0][(uu[r] >> 8) & 0xFFFu], 1u);
  __syncthreads();  // B15
  scan4096(hist3, 0, tid, lane, wv, sW3, v40, ps0, in0);
  __syncthreads();  // B16
  resolve4096(sW3, 0, tid, wv, v40, ps0, in0, kq2, &selB[0][3], &selK[0][3]);
  __syncthreads();  // B17
  unsigned q2 = selB[0][3], kq3 = selK[0][3];
  unsigned qf = (q1 << 12) | q2;
#pragma unroll
  for (int r = 0; r < 4; ++r)
    if (uu[r] != NOINS && (uu[r] >> 8) == qf) atomicAdd(&hist3[0][uu[r] & 0xFFu], 1u);
  __syncthreads();  // B18
  scan256(hist3, 0, tid, lane, wv, sW3, s80, in0);
  __syncthreads();  // B19
  resolve256(sW3, 0, tid, wv, s80, in0, kq3, &selB[1][3]);
  __syncthreads();  // B20
  float kth4 = fabsf(__uint_as_float((q1 << 20) | (q2 << 8) | selB[1][3]));
  float scale4 = fmaxf((kth4 < 1e-6f) ? mx4 : kth4, 1e-6f);
  // ---- final blend: rule + smoothed learned -> out ----
  float* orow = out + (size_t)b * T_;
#pragma unroll
  for (int r = 0; r < 4; ++r) {
    int t = tid + 1024 * r;
    float rv = (n > 0) ? sm[r] / scale4 : 0.f;
    rv = clip01(rv) * mreg[r];
    float ssum = 0.f;
#pragma unroll
    for (int d = -2; d <= 2; ++d) {
      int tt = t + d;
      if (tt >= 0 && tt < T_) ssum += vbuf[tt];
    }
    float learned = clip01(ssum * 0.2f * mreg[r]);
    orow[t] = clip01(0.5f * rv + 0.5f * learned) * mreg[r];
  }
}

}  // namespace

extern "C" void kernel_launch(void* const* d_in, const int* in_sizes, int n_in,
                              void* d_out, int out_size, void* d_ws, size_t ws_size,
                              hipStream_t stream) {
  const float* traj      = (const float*)d_in[0];
  const float* intervals = (const float*)d_in[1];
  const float* amask     = (const float*)d_in[2];
  const float* omask     = (const float*)d_in[3];
  const float* w1        = (const float*)d_in[4];
  const float* b1        = (const float*)d_in[5];
  const float* w2        = (const float*)d_in[6];
  const float* b2        = (const float*)d_in[7];
  const float* w3        = (const float*)d_in[8];
  const float* b3        = (const float*)d_in[9];
  float* out = (float*)d_out;
  float* ws = (float*)d_ws;

  _Float16* feats16 = (_Float16*)(ws + OFF_F16);
  float4* met = (float4*)(ws + OFF_MET);
  float* lp = ws + OFF_LP;
  half8* w1f = (half8*)(ws + OFF_W1F);
  half8* w2f = (half8*)(ws + OFF_W2F);

  featurize_k<<<BT / 256, 256, 0, stream>>>(traj, intervals, amask, omask, w1, w2,
                                            feats16, met, w1f, w2f);
  conv_k<<<dim3(T_ / CT, B_), 256, 0, stream>>>(feats16, w1f, b1, w2f, b2, w3, b3,
                                                amask, lp);
  ruleselect_k<<<B_, 1024, 0, stream>>>(met, amask, lp, out);
}

// Round 15
// 148.896 us; speedup vs baseline: 1.1044x; 1.1044x over previous
//
#include <hip/hip_runtime.h>

namespace {

constexpr int B_ = 128;
constexpr int T_ = 4096;
constexpr int BT = B_ * T_;
constexpr int CT = 64;  // conv t-tile (4-wave blocks, 7 blocks/CU)
constexpr unsigned NOINS = 0xFFFFFFFFu;  // "do not insert" sentinel (invalid/masked lane)

// workspace layout (float offsets)
constexpr size_t OFF_W1F = 0;                     // 8 frags * 64 * 8 f16
constexpr size_t OFF_W2F = 2048;                  // 40 frags * 64 * 8 f16
constexpr size_t OFF_F16 = 16384;                 // feats16: B*T*10 halfs = B*T*5 dwords
constexpr size_t OFF_MET = OFF_F16 + (size_t)BT * 5;   // met: float4 per (b,t)
constexpr size_t OFF_LP  = OFF_MET + (size_t)BT * 4;

typedef _Float16 half8 __attribute__((ext_vector_type(8)));
typedef _Float16 half4 __attribute__((ext_vector_type(4)));
typedef _Float16 half2_t __attribute__((ext_vector_type(2)));
typedef float f32x4 __attribute__((ext_vector_type(4)));

__device__ __forceinline__ float clip01(float x) { return fminf(fmaxf(x, 0.f), 1.f); }

// tanh-GELU as sigmoid: x*sigmoid(1.5957691*(x+0.044715x^3)), 7 VALU ops.
__device__ __forceinline__ float gelu_tanh(float x) {
  float x2 = x * x;
  float q = x * __builtin_fmaf(-0.10294444f, x2, -2.3022077f);
  float e = __builtin_amdgcn_exp2f(q);
  return x * __builtin_amdgcn_rcpf(1.0f + e);
}

// rcp + one Newton step: <=1 ulp vs exact divide for normal inputs (dt >= 1e-3)
__device__ __forceinline__ float rcp_nr(float d) {
  float r = __builtin_amdgcn_rcpf(d);
  return r * __builtin_fmaf(-d, r, 2.0f);
}

// |atan2(y,x)| in [0,pi]; poly err <= ~1e-5 rad; exact corner semantics.
__device__ __forceinline__ float fabs_atan2_fast(float y, float x) {
  float ay = fabsf(y), ax = fabsf(x);
  float mn = fminf(ax, ay), mx = fmaxf(ax, ay);
  float rc = rcp_nr(mx);
  float r = (mx > 0.f) ? mn * rc : 0.f;
  float s = r * r;
  float p = __builtin_fmaf(s, -0.01172120f, 0.05265332f);
  p = __builtin_fmaf(s, p, -0.11643287f);
  p = __builtin_fmaf(s, p, 0.19354346f);
  p = __builtin_fmaf(s, p, -0.33262347f);
  p = __builtin_fmaf(s, p, 0.99997726f);
  float t = r * p;
  if (ay > ax) t = 1.5707963267948966f - t;
  if (x < 0.f) t = 3.141592653589793f - t;
  return t;
}

// feature math for (b,t) — same values as round-4 featurize_k (float2 traj loads)
__device__ __forceinline__ void compute_feats(
    const float* __restrict__ tr, const float* __restrict__ iv,
    const float* __restrict__ mk, const float* __restrict__ om, int t,
    float* __restrict__ f /*10*/, float* anv_out, float* scv_out, float* otv_out) {
  const float2* tr2 = reinterpret_cast<const float2*>(tr);
  float m  = mk[t];
  float m1 = (t >= 1) ? mk[t - 1] : 0.f;
  float m2 = (t >= 2) ? mk[t - 2] : 0.f;
  float pm01 = (m > 0.5f && m1 > 0.5f) ? 1.f : 0.f;
  float pm12 = (m1 > 0.5f && m2 > 0.5f) ? 1.f : 0.f;
  float2 p0 = tr2[t];
  float x0x = p0.x * m, x0y = p0.y * m;
  float x1x = 0.f, x1y = 0.f, x2x = 0.f, x2y = 0.f;
  if (t >= 1) { float2 p1 = tr2[t - 1]; x1x = p1.x * m1; x1y = p1.y * m1; }
  if (t >= 2) { float2 p2 = tr2[t - 2]; x2x = p2.x * m2; x2y = p2.y * m2; }
  float dt0 = fmaxf(iv[t], 1e-3f);
  float dt1 = (t >= 1) ? fmaxf(iv[t - 1], 1e-3f) : 1e-3f;
  float inv0 = rcp_nr(dt0);
  float inv1 = rcp_nr(dt1);
  float vx = 0.f, vy = 0.f, v1x = 0.f, v1y = 0.f;
  if (t >= 1) { vx = (x0x - x1x) * pm01 * inv0 * m; vy = (x0y - x1y) * pm01 * inv0 * m; }
  if (t >= 2) { v1x = (x1x - x2x) * pm12 * inv1 * m1; v1y = (x1y - x2y) * pm12 * inv1 * m1; }
  float ax = 0.f, ay = 0.f;
  if (t >= 1) { ax = (vx - v1x) * pm01 * inv0 * m; ay = (vy - v1y) * pm01 * inv0 * m; }
  float s2 = vx * vx + vy * vy;
  float speed = (s2 > 0.f ? sqrtf(s2) : 0.f) * m;
  float s21 = v1x * v1x + v1y * v1y;
  float speed1 = (s21 > 0.f ? sqrtf(s21) : 0.f) * m1;
  float scv = (t >= 1) ? fabsf((speed - speed1) * pm01) * m : 0.f;
  float a2 = ax * ax + ay * ay;
  float anv = (a2 > 0.f ? sqrtf(a2) : 0.f) * m;
  float hcv = 0.f;
  if (t >= 1) {
    bool z0 = (vx == 0.f && vy == 0.f);
    bool z1 = (v1x == 0.f && v1y == 0.f);
    float yy, xx;
    if (z1)      { yy = vy;  xx = vx; }
    else if (z0) { yy = v1y; xx = v1x; }
    else { yy = vy * v1x - vx * v1y; xx = vx * v1x + vy * v1y; }
    hcv = fabs_atan2_fast(yy, xx) * pm01 * m;
  }
  float obs = om[t] * m;
  float otv = (t >= 1) ? fminf(fabsf(om[t] - om[t - 1]) * pm01 * m, 1.f) : 0.f;
  float itf = iv[t] * m;
  f[0] = x0x; f[1] = x0y; f[2] = vx; f[3] = vy; f[4] = ax; f[5] = ay;
  f[6] = speed; f[7] = hcv; f[8] = itf; f[9] = obs;
  *anv_out = anv; *scv_out = scv; *otv_out = otv;
}

// ---------------- Kernel A: featurize -> f16 feats + packed float4 metrics + repack ----------------
__global__ __launch_bounds__(256)
void featurize_k(const float* __restrict__ traj, const float* __restrict__ intervals,
                 const float* __restrict__ amask, const float* __restrict__ omask,
                 const float* __restrict__ w1g, const float* __restrict__ w2g,
                 _Float16* __restrict__ feats16, float4* __restrict__ met,
                 half8* __restrict__ w1f, half8* __restrict__ w2f) {
  int idx = blockIdx.x * 256 + threadIdx.x;
  int b = idx >> 12;
  int t = idx & (T_ - 1);
  float f[10], anv, scv, otv;
  compute_feats(traj + (size_t)b * T_ * 2, intervals + (size_t)b * T_,
                amask + (size_t)b * T_, omask + (size_t)b * T_, t, f, &anv, &scv, &otv);
  half2_t* fd = reinterpret_cast<half2_t*>(feats16) + (size_t)idx * 5;
#pragma unroll
  for (int q = 0; q < 5; ++q) {
    half2_t pk;
    pk[0] = (_Float16)(f[2 * q] * 0.015625f);
    pk[1] = (_Float16)(f[2 * q + 1] * 0.015625f);
    fd[q] = pk;
  }
  met[idx] = make_float4(f[7], anv, scv, otv);

  if (blockIdx.x < 12) {
    int gid = blockIdx.x * 256 + threadIdx.x;
    if (gid < 48 * 64) {
      int fid = gid >> 6, lane = gid & 63;
      int qd = lane >> 4, ln = lane & 15;
      half8 v;
      if (fid < 8) {
        int m = fid >> 1, kk = fid & 1;
        int o = m * 16 + ln;
#pragma unroll
        for (int j = 0; j < 8; ++j) {
          int ck = kk * 32 + qd * 8 + j;
          float val = 0.f;
          if (ck < 50) { int k_ = ck / 10, c = ck - 10 * k_; val = w1g[o * 50 + c * 5 + k_]; }
          v[j] = (_Float16)val;
        }
        w1f[fid * 64 + lane] = v;
      } else {
        int f2 = fid - 8;
        int k = f2 >> 3, kk = (f2 >> 2) & 1, m = f2 & 3;
        int o = m * 16 + ln;
#pragma unroll
        for (int j = 0; j < 8; ++j) {
          int ic = kk * 32 + qd * 8 + j;
          v[j] = (_Float16)w2g[o * 320 + ic * 5 + k];
        }
        w2f[f2 * 64 + lane] = v;
      }
    }
  }
}

// ---------------- Kernel B: MFMA conv stack, CT=64 / 4-wave blocks (R13 version) ----------------
// Phase-2 wave = (m-pair p, n-pair nq): 2 A-glob + 2 B-LDS per iter. R14's B-minimal
// mapping regressed (global A latency > LDS B cost at 36 VGPR) — keep this mapping.
__global__ __launch_bounds__(256, 7)
void conv_k(const _Float16* __restrict__ feats16, const half8* __restrict__ w1f,
            const float* __restrict__ b1g, const half8* __restrict__ w2f,
            const float* __restrict__ b2g, const float* __restrict__ w3g,
            const float* __restrict__ b3g, const float* __restrict__ amask,
            float* __restrict__ lp) {
  __shared__ _Float16 sIm[80 * 72];    // 11520 B
  __shared__ _Float16 sH1[68 * 72];    // 9792 B
  __shared__ float sPart[2][64];
  _Float16* sF16 = sH1;  // staging tile aliases sH1 until im2col barrier
  int tid = threadIdx.x;
  int lane = tid & 63, w = tid >> 6;
  int qd = lane >> 4, ln = lane & 15;
  int tile = blockIdx.x, b = blockIdx.y;
  int t0 = tile * CT;

  const unsigned* gfd = reinterpret_cast<const unsigned*>(feats16 + (size_t)b * T_ * 10);
  unsigned* sFd = reinterpret_cast<unsigned*>(sF16);
  int dbase = (t0 - 4) * 5;
  for (int s = tid; s < 360; s += 256) {
    int gi = dbase + s;
    sFd[s] = (gi >= 0 && gi < T_ * 5) ? gfd[gi] : 0u;
  }
  for (int s = tid; s < 560; s += 256) {
    int jt = s / 7, d = s - jt * 7;
    *reinterpret_cast<unsigned*>(&sIm[jt * 72 + 50 + 2 * d]) = 0u;
  }
  __syncthreads();
  unsigned* sId = reinterpret_cast<unsigned*>(sIm);
  for (int s = tid; s < 340; s += 256) {
    int jt = s / 5, k = s - jt * 5;
    const unsigned* src = sFd + (jt + k) * 5;
    unsigned* dst = sId + jt * 36 + k * 5;
#pragma unroll
    for (int q = 0; q < 5; ++q) dst[q] = src[q];
  }
  __syncthreads();  // sF16 dead; sH1 writes may begin

  // ---- phase 1: conv1; wave w owns output-channel group m = w ----
  {
    int m = w;
    half8 a1k0 = w1f[(m * 2 + 0) * 64 + lane];
    half8 a1k1 = w1f[(m * 2 + 1) * 64 + lane];
    f32x4 bv = *reinterpret_cast<const f32x4*>(&b1g[m * 16 + qd * 4]);
    f32x4 b1s;
#pragma unroll
    for (int r = 0; r < 4; ++r) b1s[r] = bv[r] * 0.015625f;
#pragma unroll
    for (int tl = 0; tl < 5; ++tl) {
      int jt = tl * 16 + ln;
      half8 bf0 = *reinterpret_cast<const half8*>(&sIm[jt * 72 + qd * 8]);
      half8 bf1 = *reinterpret_cast<const half8*>(&sIm[jt * 72 + 32 + qd * 8]);
      f32x4 acc = b1s;
      acc = __builtin_amdgcn_mfma_f32_16x16x32_f16(a1k0, bf0, acc, 0, 0, 0);
      acc = __builtin_amdgcn_mfma_f32_16x16x32_f16(a1k1, bf1, acc, 0, 0, 0);
      if (jt < 68) {
        int t = t0 - 2 + jt;
        bool inr = (t >= 0 && t < T_);
        half4 hv;
#pragma unroll
        for (int r = 0; r < 4; ++r) {
          float h = inr ? gelu_tanh(acc[r] * 64.f) * 0.0625f : 0.f;
          hv[r] = (_Float16)h;
        }
        *reinterpret_cast<half4*>(&sH1[jt * 72 + m * 16 + qd * 4]) = hv;
      }
    }
  }
  __syncthreads();

  // ---- phase 2: conv2 as 5 shifted GEMMs; wave = (p, nq) ----
  int p = w & 1, nq = w >> 1;
  f32x4 acc2[2][2];
#pragma unroll
  for (int dm = 0; dm < 2; ++dm) {
    f32x4 bv = *reinterpret_cast<const f32x4*>(&b2g[(2 * p + dm) * 16 + qd * 4]);
#pragma unroll
    for (int dn = 0; dn < 2; ++dn)
#pragma unroll
      for (int r = 0; r < 4; ++r) acc2[dm][dn][r] = bv[r] * 0.0625f;
  }
#pragma unroll
  for (int k = 0; k < 5; ++k) {
#pragma unroll
    for (int kk = 0; kk < 2; ++kk) {
      half8 A0 = w2f[((k * 2 + kk) * 4 + 2 * p + 0) * 64 + lane];
      half8 A1 = w2f[((k * 2 + kk) * 4 + 2 * p + 1) * 64 + lane];
      half8 B0 = *reinterpret_cast<const half8*>(
          &sH1[((2 * nq + 0) * 16 + ln + k) * 72 + kk * 32 + qd * 8]);
      half8 B1 = *reinterpret_cast<const half8*>(
          &sH1[((2 * nq + 1) * 16 + ln + k) * 72 + kk * 32 + qd * 8]);
      acc2[0][0] = __builtin_amdgcn_mfma_f32_16x16x32_f16(A0, B0, acc2[0][0], 0, 0, 0);
      acc2[0][1] = __builtin_amdgcn_mfma_f32_16x16x32_f16(A0, B1, acc2[0][1], 0, 0, 0);
      acc2[1][0] = __builtin_amdgcn_mfma_f32_16x16x32_f16(A1, B0, acc2[1][0], 0, 0, 0);
      acc2[1][1] = __builtin_amdgcn_mfma_f32_16x16x32_f16(A1, B1, acc2[1][1], 0, 0, 0);
    }
  }
  f32x4 w3a = *reinterpret_cast<const f32x4*>(&w3g[(2 * p + 0) * 16 + qd * 4]);
  f32x4 w3b = *reinterpret_cast<const f32x4*>(&w3g[(2 * p + 1) * 16 + qd * 4]);
#pragma unroll
  for (int dn = 0; dn < 2; ++dn) {
    float s = 0.f;
#pragma unroll
    for (int r = 0; r < 4; ++r) s += w3a[r] * gelu_tanh(acc2[0][dn][r] * 16.f);
#pragma unroll
    for (int r = 0; r < 4; ++r) s += w3b[r] * gelu_tanh(acc2[1][dn][r] * 16.f);
    s += __shfl_xor(s, 16);
    s += __shfl_xor(s, 32);
    if (lane < 16) sPart[p][(2 * nq + dn) * 16 + lane] = s;
  }
  __syncthreads();
  if (tid < 64) {
    int t = t0 + tid;
    float logit = sPart[0][tid] + sPart[1][tid] + b3g[0];
    float m = amask[(size_t)b * T_ + t];
    float e = __builtin_amdgcn_exp2f(logit * -1.4426950408889634f);
    lp[(size_t)b * T_ + t] = m * __builtin_amdgcn_rcpf(1.f + e);
  }
}

// ---------------- low-barrier radix-select machinery ----------------
__device__ __forceinline__ void scan4096(unsigned (*hist)[4096], int j, int tid, int lane,
                                         int wv, unsigned (*sW)[16], uint4& v,
                                         unsigned& ps, unsigned& incl) {
  v = *reinterpret_cast<uint4*>(&hist[j][tid * 4]);
  uint4 zz = {0u, 0u, 0u, 0u};
  *reinterpret_cast<uint4*>(&hist[j][tid * 4]) = zz;
  ps = v.x + v.y + v.z + v.w;
  incl = ps;
#pragma unroll
  for (int off = 1; off < 64; off <<= 1) {
    unsigned tv = __shfl_up(incl, off, 64);
    if (lane >= off) incl += tv;
  }
  if (lane == 63) sW[j][wv] = incl;
}
__device__ __forceinline__ void resolve4096(const unsigned (*sW)[16], int j, int tid, int wv,
                                            uint4 v, unsigned ps, unsigned incl, unsigned k,
                                            unsigned* selb, unsigned* selk) {
  unsigned woff = 0;
  for (int i = 0; i < wv; ++i) woff += sW[j][i];
  incl += woff;
  unsigned excl = incl - ps;
  if (excl <= k && k < incl) {
    unsigned vv[4] = {v.x, v.y, v.z, v.w};
    unsigned run = excl;
    int c = 0;
#pragma unroll
    for (; c < 3; ++c) {
      if (run + vv[c] > k) break;
      run += vv[c];
    }
    *selb = (unsigned)(tid * 4 + c);
    *selk = k - run;
  }
}
__device__ __forceinline__ void scan256(unsigned (*hist)[4096], int j, int tid, int lane,
                                        int wv, unsigned (*sW)[16], unsigned& v,
                                        unsigned& incl) {
  v = (tid < 256) ? hist[j][tid] : 0u;
  if (tid < 256) hist[j][tid] = 0u;
  incl = v;
#pragma unroll
  for (int off = 1; off < 64; off <<= 1) {
    unsigned tv = __shfl_up(incl, off, 64);
    if (lane >= off) incl += tv;
  }
  if (lane == 63) sW[j][wv] = incl;
}
__device__ __forceinline__ void resolve256(const unsigned (*sW)[16], int j, int tid, int wv,
                                           unsigned v, unsigned incl, unsigned k,
                                           unsigned* selb) {
  unsigned woff = 0;
  for (int i = 0; i < wv; ++i) woff += sW[j][i];
  incl += woff;
  unsigned excl = incl - v;
  if (excl <= k && k < incl) *selb = (unsigned)tid;
}

// ---------------- Kernel C: selects + smooth + normalize + FINAL BLEND (per row) ----------------
__global__ __launch_bounds__(1024)
void ruleselect_k(const float4* __restrict__ met, const float* __restrict__ amask,
                  const float* __restrict__ lp, float* __restrict__ out) {
  __shared__ unsigned hist3[3][4096];
  __shared__ float vbuf[4096];
  __shared__ unsigned selB[2][4];
  __shared__ unsigned selK[2][4];
  __shared__ unsigned sW3[3][16];
  __shared__ float sM3[3][16];
  __shared__ int iCnt[16];
  int b = blockIdx.x, tid = threadIdx.x;
  int lane = tid & 63, wv = tid >> 6;
  const float* mk = amask + (size_t)b * T_;
  const float4* mrow = met + (size_t)b * T_;

  float mv0[4], mv1[4], mv2[4], otv[4], mreg[4];
  int cnt = 0;
#pragma unroll
  for (int r = 0; r < 4; ++r) {
    int t = tid + 1024 * r;
    float4 v = mrow[t];
    mv0[r] = v.x; mv1[r] = v.y; mv2[r] = v.z; otv[r] = v.w;
    mreg[r] = mk[t];
    cnt += (mreg[r] > 0.5f);
  }
#pragma unroll
  for (int off = 32; off; off >>= 1) cnt += __shfl_xor(cnt, off);
  if (lane == 0) iCnt[wv] = cnt;
  {
    unsigned* hflat = &hist3[0][0];
    for (int i = tid; i < 3 * 4096; i += 1024) hflat[i] = 0u;
  }
  unsigned u0[4], u1[4], u2[4];
  float mxa = 0.f, mxb = 0.f, mxc = 0.f;
#pragma unroll
  for (int r = 0; r < 4; ++r) {
    bool valid = mreg[r] > 0.5f;
    unsigned b0 = __float_as_uint(mv0[r]); if ((int)b0 < 0) b0 = 0u;
    unsigned b1 = __float_as_uint(mv1[r]); if ((int)b1 < 0) b1 = 0u;
    unsigned b2 = __float_as_uint(mv2[r]); if ((int)b2 < 0) b2 = 0u;
    u0[r] = valid ? b0 : NOINS;
    u1[r] = valid ? b1 : NOINS;
    u2[r] = valid ? b2 : NOINS;
    if (valid) {
      mxa = fmaxf(mxa, fabsf(mv0[r]));
      mxb = fmaxf(mxb, fabsf(mv1[r]));
      mxc = fmaxf(mxc, fabsf(mv2[r]));
    }
  }
#pragma unroll
  for (int off = 32; off; off >>= 1) {
    mxa = fmaxf(mxa, __shfl_xor(mxa, off));
    mxb = fmaxf(mxb, __shfl_xor(mxb, off));
    mxc = fmaxf(mxc, __shfl_xor(mxc, off));
  }
  if (lane == 0) { sM3[0][wv] = mxa; sM3[1][wv] = mxb; sM3[2][wv] = mxc; }
  __syncthreads();  // B1
  int n = 0;
#pragma unroll
  for (int i = 0; i < 16; ++i) n += iCnt[i];
  int cidx = (int)ceilf((float)n * 0.95f);
  if (cidx < 1) cidx = 1;
  unsigned kidx = (unsigned)(cidx - 1);
  if (kidx > (unsigned)(T_ - 1)) kidx = T_ - 1;
  float mx3a = sM3[0][0], mx3b = sM3[1][0], mx3c = sM3[2][0];
#pragma unroll
  for (int i = 1; i < 16; ++i) {
    mx3a = fmaxf(mx3a, sM3[0][i]);
    mx3b = fmaxf(mx3b, sM3[1][i]);
    mx3c = fmaxf(mx3c, sM3[2][i]);
  }

#pragma unroll
  for (int r = 0; r < 4; ++r) {
    if (u0[r] != NOINS) atomicAdd(&hist3[0][u0[r] >> 20], 1u);
    if (u1[r] != NOINS) atomicAdd(&hist3[1][u1[r] >> 20], 1u);
    if (u2[r] != NOINS) atomicAdd(&hist3[2][u2[r] >> 20], 1u);
  }
  __syncthreads();  // B2
  uint4 v40, v41, v42; unsigned ps0, ps1, ps2, in0, in1, in2;
  scan4096(hist3, 0, tid, lane, wv, sW3, v40, ps0, in0);
  scan4096(hist3, 1, tid, lane, wv, sW3, v41, ps1, in1);
  scan4096(hist3, 2, tid, lane, wv, sW3, v42, ps2, in2);
  __syncthreads();  // B3
  resolve4096(sW3, 0, tid, wv, v40, ps0, in0, kidx, &selB[1][0], &selK[1][0]);
  resolve4096(sW3, 1, tid, wv, v41, ps1, in1, kidx, &selB[1][1], &selK[1][1]);
  resolve4096(sW3, 2, tid, wv, v42, ps2, in2, kidx, &selB[1][2], &selK[1][2]);
  __syncthreads();  // B4
  unsigned p1_0 = selB[1][0], p1_1 = selB[1][1], p1_2 = selB[1][2];
  unsigned k2_0 = selK[1][0], k2_1 = selK[1][1], k2_2 = selK[1][2];
#pragma unroll
  for (int r = 0; r < 4; ++r) {
    if (u0[r] != NOINS && (u0[r] >> 20) == p1_0) atomicAdd(&hist3[0][(u0[r] >> 8) & 0xFFFu], 1u);
    if (u1[r] != NOINS && (u1[r] >> 20) == p1_1) atomicAdd(&hist3[1][(u1[r] >> 8) & 0xFFFu], 1u);
    if (u2[r] != NOINS && (u2[r] >> 20) == p1_2) atomicAdd(&hist3[2][(u2[r] >> 8) & 0xFFFu], 1u);
  }
  __syncthreads();  // B5
  scan4096(hist3, 0, tid, lane, wv, sW3, v40, ps0, in0);
  scan4096(hist3, 1, tid, lane, wv, sW3, v41, ps1, in1);
  scan4096(hist3, 2, tid, lane, wv, sW3, v42, ps2, in2);
  __syncthreads();  // B6
  resolve4096(sW3, 0, tid, wv, v40, ps0, in0, k2_0, &selB[0][0], &selK[0][0]);
  resolve4096(sW3, 1, tid, wv, v41, ps1, in1, k2_1, &selB[0][1], &selK[0][1]);
  resolve4096(sW3, 2, tid, wv, v42, ps2, in2, k2_2, &selB[0][2], &selK[0][2]);
  __syncthreads();  // B7
  unsigned p2_0 = selB[0][0], p2_1 = selB[0][1], p2_2 = selB[0][2];
  unsigned k3_0 = selK[0][0], k3_1 = selK[0][1], k3_2 = selK[0][2];
  unsigned pf0 = (p1_0 << 12) | p2_0, pf1 = (p1_1 << 12) | p2_1, pf2 = (p1_2 << 12) | p2_2;
#pragma unroll
  for (int r = 0; r < 4; ++r) {
    if (u0[r] != NOINS && (u0[r] >> 8) == pf0) atomicAdd(&hist3[0][u0[r] & 0xFFu], 1u);
    if (u1[r] != NOINS && (u1[r] >> 8) == pf1) atomicAdd(&hist3[1][u1[r] & 0xFFu], 1u);
    if (u2[r] != NOINS && (u2[r] >> 8) == pf2) atomicAdd(&hist3[2][u2[r] & 0xFFu], 1u);
  }
  __syncthreads();  // B8
  unsigned s80, s81, s82;
  scan256(hist3, 0, tid, lane, wv, sW3, s80, in0);
  scan256(hist3, 1, tid, lane, wv, sW3, s81, in1);
  scan256(hist3, 2, tid, lane, wv, sW3, s82, in2);
  __syncthreads();  // B9
  resolve256(sW3, 0, tid, wv, s80, in0, k3_0, &selB[1][0]);
  resolve256(sW3, 1, tid, wv, s81, in1, k3_1, &selB[1][1]);
  resolve256(sW3, 2, tid, wv, s82, in2, k3_2, &selB[1][2]);
  __syncthreads();  // B10
  float kth0 = fabsf(__uint_as_float((p1_0 << 20) | (p2_0 << 8) | selB[1][0]));
  float kth1 = fabsf(__uint_as_float((p1_1 << 20) | (p2_1 << 8) | selB[1][1]));
  float kth2 = fabsf(__uint_as_float((p1_2 << 20) | (p2_2 << 8) | selB[1][2]));
  float sc0 = fmaxf((kth0 < 1e-6f) ? mx3a : kth0, 1e-6f);
  float sc1 = fmaxf((kth1 < 1e-6f) ? mx3b : kth1, 1e-6f);
  float sc2 = fmaxf((kth2 < 1e-6f) ? mx3c : kth2, 1e-6f);

#pragma unroll
  for (int r = 0; r < 4; ++r) {
    int t = tid + 1024 * r;
    float v = 0.f;
    if (n > 0) {
      v = 0.35f * (mv0[r] / sc0) + 0.30f * (mv1[r] / sc1)
        + 0.25f * (mv2[r] / sc2) + 0.10f * otv[r];
    }
    vbuf[t] = v;
  }
  __syncthreads();  // B11
  float sm[4];
#pragma unroll
  for (int r = 0; r < 4; ++r) {
    int t = tid + 1024 * r;
    float s = 0.f;
#pragma unroll
    for (int d = -2; d <= 2; ++d) {
      int tt = t + d;
      if (tt >= 0 && tt < T_) s += vbuf[tt];
    }
    sm[r] = s * 0.2f * mreg[r];
  }
  // ---- 4th select (hist3[0], slot 3) ----
  unsigned uu[4];
  float mxs = 0.f;
#pragma unroll
  for (int r = 0; r < 4; ++r) {
    bool valid = mreg[r] > 0.5f;
    unsigned ub = __float_as_uint(sm[r]); if ((int)ub < 0) ub = 0u;
    uu[r] = valid ? ub : NOINS;
    if (valid) mxs = fmaxf(mxs, fabsf(sm[r]));
  }
#pragma unroll
  for (int off = 32; off; off >>= 1) mxs = fmaxf(mxs, __shfl_xor(mxs, off));
  if (lane == 0) sM3[0][wv] = mxs;
#pragma unroll
  for (int r = 0; r < 4; ++r)
    if (uu[r] != NOINS) atomicAdd(&hist3[0][uu[r] >> 20], 1u);
  __syncthreads();  // B12 — smooth reads of vbuf done; repurpose vbuf for lp
  const float* lprow = lp + (size_t)b * T_;
#pragma unroll
  for (int r = 0; r < 4; ++r) {
    int t = tid + 1024 * r;
    vbuf[t] = lprow[t];
  }
  float mx4 = sM3[0][0];
#pragma unroll
  for (int i = 1; i < 16; ++i) mx4 = fmaxf(mx4, sM3[0][i]);
  scan4096(hist3, 0, tid, lane, wv, sW3, v40, ps0, in0);
  __syncthreads();  // B13
  resolve4096(sW3, 0, tid, wv, v40, ps0, in0, kidx, &selB[1][3], &selK[1][3]);
  __syncthreads();  // B14
  unsigned q1 = selB[1][3], kq2 = selK[1][3];
#pragma unroll
  for (int r = 0; r < 4; ++r)
    if (uu[r] != NOINS && (uu[r] >> 20) == q1) atomicAdd(&hist3[0][(uu[r] >> 8) & 0xFFFu], 1u);
  __syncthreads();  // B15
  scan4096(hist3, 0, tid, lane, wv, sW3, v40, ps0, in0);
  __syncthreads();  // B16
  resolve4096(sW3, 0, tid, wv, v40, ps0, in0, kq2, &selB[0][3], &selK[0][3]);
  __syncthreads();  // B17
  unsigned q2 = selB[0][3], kq3 = selK[0][3];
  unsigned qf = (q1 << 12) | q2;
#pragma unroll
  for (int r = 0; r < 4; ++r)
    if (uu[r] != NOINS && (uu[r] >> 8) == qf) atomicAdd(&hist3[0][uu[r] & 0xFFu], 1u);
  __syncthreads();  // B18
  scan256(hist3, 0, tid, lane, wv, sW3, s80, in0);
  __syncthreads();  // B19
  resolve256(sW3, 0, tid, wv, s80, in0, kq3, &selB[1][3]);
  __syncthreads();  // B20
  float kth4 = fabsf(__uint_as_float((q1 << 20) | (q2 << 8) | selB[1][3]));
  float scale4 = fmaxf((kth4 < 1e-6f) ? mx4 : kth4, 1e-6f);
  // ---- final blend: rule + smoothed learned -> out ----
  float* orow = out + (size_t)b * T_;
#pragma unroll
  for (int r = 0; r < 4; ++r) {
    int t = tid + 1024 * r;
    float rv = (n > 0) ? sm[r] / scale4 : 0.f;
    rv = clip01(rv) * mreg[r];
    float ssum = 0.f;
#pragma unroll
    for (int d = -2; d <= 2; ++d) {
      int tt = t + d;
      if (tt >= 0 && tt < T_) ssum += vbuf[tt];
    }
    float learned = clip01(ssum * 0.2f * mreg[r]);
    orow[t] = clip01(0.5f * rv + 0.5f * learned) * mreg[r];
  }
}

}  // namespace

extern "C" void kernel_launch(void* const* d_in, const int* in_sizes, int n_in,
                              void* d_out, int out_size, void* d_ws, size_t ws_size,
                              hipStream_t stream) {
  const float* traj      = (const float*)d_in[0];
  const float* intervals = (const float*)d_in[1];
  const float* amask     = (const float*)d_in[2];
  const float* omask     = (const float*)d_in[3];
  const float* w1        = (const float*)d_in[4];
  const float* b1        = (const float*)d_in[5];
  const float* w2        = (const float*)d_in[6];
  const float* b2        = (const float*)d_in[7];
  const float* w3        = (const float*)d_in[8];
  const float* b3        = (const float*)d_in[9];
  float* out = (float*)d_out;
  float* ws = (float*)d_ws;

  _Float16* feats16 = (_Float16*)(ws + OFF_F16);
  float4* met = (float4*)(ws + OFF_MET);
  float* lp = ws + OFF_LP;
  half8* w1f = (half8*)(ws + OFF_W1F);
  half8* w2f = (half8*)(ws + OFF_W2F);

  featurize_k<<<BT / 256, 256, 0, stream>>>(traj, intervals, amask, omask, w1, w2,
                                            feats16, met, w1f, w2f);
  conv_k<<<dim3(T_ / CT, B_), 256, 0, stream>>>(feats16, w1f, b1, w2f, b2, w3, b3,
                                                amask, lp);
  ruleselect_k<<<B_, 1024, 0, stream>>>(met, amask, lp, out);
}